// Round 8
// baseline (55.371 us; speedup 1.0000x reference)
//
#include <hip/hip_runtime.h>
#include <math.h>
#include <complex>

#define T_STEPS 16384
#define BATCH   512
#define KF      5
#define TAU     (T_STEPS + KF - 1)   /* 16388 */
#define NCHUNK  512
#define CHLEN   (T_STEPS / NCHUNK)   /* 32 */
#define NTAU    (CHLEN + KF - 1)     /* 36 taus per chunk = 9 float4 */
#define NSER    12                   /* rho(M)^NSER = 0.148^12 ~ 1e-10 */

struct Coefs {
    double b0, b1, b2, b3, b4;   /* FIR numerator */
    double c0, c1, c2, c3;       /* a_rev[:-1] = [a4,a3,a2,a1] */
};
struct Mat { double m[16]; };    /* m[j*4+i]: init-state j -> end-state i, M = S^CHLEN */

/* XCD-bijective swizzle (NCHUNK % 8 == 0): runs of 64 consecutive chunks share
   an XCD -> pend neighbor reads are L2-local. */
__device__ __forceinline__ int swz_chunk(int w) { return (w & 7) * (NCHUNK / 8) + (w >> 3); }

/* ---- K1: sd[tau] once for the whole grid; one wave per tau ---- */
__global__ __launch_bounds__(256) void k_sd(const float* __restrict__ signal,
                                            double* __restrict__ sd) {
    const int wave = threadIdx.x >> 6;
    const int lane = threadIdx.x & 63;
    const int tau  = blockIdx.x * 4 + wave;
    if (tau >= TAU) return;
    float m = 0.0f;
    if (tau >= 4) {
        const float4* p = (const float4*)(signal + (size_t)(tau - 4) * BATCH);
        const float4 a = p[lane], bq = p[lane + 64];
        float v = (a.x + a.y) + (a.z + a.w) + (bq.x + bq.y) + (bq.z + bq.w);
        for (int off = 32; off > 0; off >>= 1) v += __shfl_down(v, off, 64);
        m = v;
    }
    if (lane == 0) {
        const double c1 = 2.0 * 1.602176563e-19 * 50000000000.0;
        const double c2 = 4.0 * 1.3806488e-23 * 300.0 * 50000000000.0 / 1000000.0;
        sd[tau] = sqrt(c1 * ((double)m / 512.0 + 1e-10) + c2);
    }
}

/* ---- streaming FIR + IIR body shared by k_pend / k_out ----
   Thread (c,b): stream xn(j) = sd[j]*noise[b][t0+j] + sig(j) through the
   5-tap FIR and the 4-state IIR, init state given. No per-thread arrays. */
template <bool WRITE_OUT>
__device__ __forceinline__ void run_chunk(const float* __restrict__ signal,
                                          const float* __restrict__ noise,
                                          const double* __restrict__ sdsh,
                                          const Coefs& k, int c, int b,
                                          double& z0, double& z1, double& z2, double& z3,
                                          float* __restrict__ out) {
    const int t0 = c * CHLEN;
    const float4* nb = (const float4*)(noise + (size_t)b * TAU + t0);

    auto SIG = [&](int j) -> double {
        const int tau = t0 + j;
        return (c == 0 && tau < 4) ? 0.0 : (double)signal[(size_t)(tau - 4) * BATCH + b];
    };

    float4 f = nb[0];
    double w0 = sdsh[0] * (double)f.x + SIG(0);
    double w1 = sdsh[1] * (double)f.y + SIG(1);
    double w2 = sdsh[2] * (double)f.z + SIG(2);
    double w3 = sdsh[3] * (double)f.w + SIG(3);
    #pragma unroll
    for (int q = 1; q < 9; ++q) {
        f = nb[q];
        const float nf[4] = { f.x, f.y, f.z, f.w };
        #pragma unroll
        for (int u = 0; u < 4; ++u) {
            const int i = 4 * (q - 1) + u;          /* step 0..31 */
            const int j = 4 * q + u;                /* xn index i+4 */
            const double w4 = sdsh[j] * (double)nf[u] + SIG(j);
            const double s = k.b0 * w0 + k.b1 * w1 + k.b2 * w2 + k.b3 * w3 + k.b4 * w4;
            const double y = (c == 0 && i < 5) ? s
                           : s - (k.c0 * z0 + k.c1 * z1 + k.c2 * z2 + k.c3 * z3);
            z0 = z1; z1 = z2; z2 = z3; z3 = y;
            w0 = w1; w1 = w2; w2 = w3; w3 = w4;
            if (WRITE_OUT) out[(size_t)(t0 + i) * BATCH + b] = (float)y;
        }
    }
}

/* ---- K2: zero-init pass -> pend only (4 MB) ---- */
__global__ __launch_bounds__(256, 4) void k_pend(const float* __restrict__ signal,
                                                 const float* __restrict__ noise,
                                                 const double* __restrict__ sd,
                                                 const Coefs k,
                                                 float4* __restrict__ pend4) {
    __shared__ double sdsh[NTAU];
    const int tid = threadIdx.x;
    const int b   = (int)blockIdx.y * 256 + tid;
    const int c   = swz_chunk(blockIdx.x);
    if (tid < NTAU) sdsh[tid] = sd[c * CHLEN + tid];
    __syncthreads();

    double z0 = 0.0, z1 = 0.0, z2 = 0.0, z3 = 0.0;
    run_chunk<false>(signal, noise, sdsh, k, c, b, z0, z1, z2, z3, nullptr);
    pend4[(size_t)c * BATCH + b] = make_float4((float)z0, (float)z1, (float)z2, (float)z3);
}

/* ---- K3: Horner init from 12 neighbor pends + recompute FIR + replay ---- */
__global__ __launch_bounds__(256, 4) void k_out(const float* __restrict__ signal,
                                                const float* __restrict__ noise,
                                                const double* __restrict__ sd,
                                                const Coefs k, const Mat M,
                                                const float4* __restrict__ pend4,
                                                float* __restrict__ out) {
    __shared__ double sdsh[NTAU];
    const int tid = threadIdx.x;
    const int b   = (int)blockIdx.y * 256 + tid;
    const int c   = swz_chunk(blockIdx.x);
    if (tid < NTAU) sdsh[tid] = sd[c * CHLEN + tid];
    __syncthreads();

    /* y0(c) = p(c-1) + M*(p(c-2) + M*(...)), NSER terms (uniform branch per block) */
    double z0 = 0.0, z1 = 0.0, z2 = 0.0, z3 = 0.0;
    #pragma unroll
    for (int d = NSER; d >= 1; --d) {
        if (d <= c) {
            const float4 p = pend4[(size_t)(c - d) * BATCH + b];
            const double n0 = (double)p.x + M.m[0] * z0 + M.m[4] * z1 + M.m[8]  * z2 + M.m[12] * z3;
            const double n1 = (double)p.y + M.m[1] * z0 + M.m[5] * z1 + M.m[9]  * z2 + M.m[13] * z3;
            const double n2 = (double)p.z + M.m[2] * z0 + M.m[6] * z1 + M.m[10] * z2 + M.m[14] * z3;
            const double n3 = (double)p.w + M.m[3] * z0 + M.m[7] * z1 + M.m[11] * z2 + M.m[15] * z3;
            z0 = n0; z1 = n1; z2 = n2; z3 = n3;
        }
    }

    run_chunk<true>(signal, noise, sdsh, k, c, b, z0, z1, z2, z3, out);
}

/* ---- host: replicate _butter_lowpass exactly (f64, same algorithm) ---- */
static Coefs make_coefs() {
    const int order = 4;
    const double wn = 25000000000.0 / (0.5 / 1e-12);     /* 0.05 */
    const double warped = 4.0 * tan(M_PI * wn / 2.0);
    std::complex<double> p[4];
    for (int kk = 1; kk <= order; ++kk)
        p[kk - 1] = warped * std::exp(std::complex<double>(0.0,
                        M_PI * (2 * kk + order - 1) / (2.0 * order)));
    const double gain = warped * warped * warped * warped;
    const double fs2 = 4.0;
    std::complex<double> pz[4], prod(1.0, 0.0);
    for (int i = 0; i < 4; ++i) {
        pz[i] = (fs2 + p[i]) / (fs2 - p[i]);
        prod *= (fs2 - p[i]);
    }
    const double gz = gain * std::real(std::complex<double>(1.0, 0.0) / prod);
    std::complex<double> ac[5] = { {1,0}, {0,0}, {0,0}, {0,0}, {0,0} };
    for (int i = 0; i < 4; ++i)
        for (int j = i + 1; j >= 1; --j)
            ac[j] = ac[j] - pz[i] * ac[j - 1];
    Coefs k;
    k.b0 = gz * 1.0; k.b1 = gz * 4.0; k.b2 = gz * 6.0; k.b3 = gz * 4.0; k.b4 = gz * 1.0;
    k.c0 = std::real(ac[4]); k.c1 = std::real(ac[3]);
    k.c2 = std::real(ac[2]); k.c3 = std::real(ac[1]);
    return k;
}

static void mat_compose(const double* P, const double* Q, double* R) {
    double t[16];
    for (int j = 0; j < 4; ++j)
        for (int i = 0; i < 4; ++i) {
            double s = 0.0;
            for (int kk = 0; kk < 4; ++kk) s += P[j*4+kk] * Q[kk*4+i];
            t[j*4+i] = s;
        }
    for (int i = 0; i < 16; ++i) R[i] = t[i];
}

static Mat make_M(const Coefs& k) {
    double S[16] = {0};
    S[1*4+0] = 1.0; S[2*4+1] = 1.0; S[3*4+2] = 1.0;
    S[0*4+3] = -k.c0; S[1*4+3] = -k.c1; S[2*4+3] = -k.c2; S[3*4+3] = -k.c3;
    Mat M;
    double I[16] = {1,0,0,0, 0,1,0,0, 0,0,1,0, 0,0,0,1};
    for (int i = 0; i < 16; ++i) M.m[i] = I[i];
    for (int i = 0; i < CHLEN; ++i) mat_compose(M.m, S, M.m);
    return M;
}

extern "C" void kernel_launch(void* const* d_in, const int* in_sizes, int n_in,
                              void* d_out, int out_size, void* d_ws, size_t ws_size,
                              hipStream_t stream) {
    const float* signal = (const float*)d_in[0];
    const float* noise  = (const float*)d_in[1];
    float* out = (float*)d_out;

    const Coefs k = make_coefs();    /* host f64 math; deterministic each call */
    const Mat   M = make_M(k);

    char* ws = (char*)d_ws;
    double* sd    = (double*)ws;                 /* 16388*8 = 131,104 B */
    float4* pend4 = (float4*)(ws + 131104);      /* 512*512*16 = 4 MB   */

    hipLaunchKernelGGL(k_sd,   dim3((TAU + 3) / 4), dim3(256), 0, stream, signal, sd);
    hipLaunchKernelGGL(k_pend, dim3(NCHUNK, 2), dim3(256), 0, stream,
                       signal, noise, sd, k, pend4);
    hipLaunchKernelGGL(k_out,  dim3(NCHUNK, 2), dim3(256), 0, stream,
                       signal, noise, sd, k, M, pend4, out);
}

// Round 9
// 45.235 us; speedup vs baseline: 1.2241x; 1.2241x over previous
//
#include <hip/hip_runtime.h>
#include <hip/hip_fp16.h>
#include <math.h>
#include <complex>

#define T_STEPS 16384
#define BATCH   512
#define KF      5
#define TAU     (T_STEPS + KF - 1)   /* 16388 */
#define NCHUNK  512
#define CHLEN   (T_STEPS / NCHUNK)   /* 32 */
#define NTAU    (CHLEN + KF - 1)     /* 36 taus per chunk = 9 float4 */
#define NSER    8                    /* rho(M)^8 = 0.145^8 ~ 2e-7, << 3.9e-3 floor */

struct Coefs {
    double b0, b1, b2, b3, b4;   /* FIR numerator */
    double c0, c1, c2, c3;       /* a_rev[:-1] = [a4,a3,a2,a1] */
};
struct Mat { double m[16]; };    /* m[j*4+i]: init-state j -> end-state i, M = S^CHLEN */

/* XCD-bijective swizzle (NCHUNK % 8 == 0): runs of 64 consecutive chunks share
   an XCD -> pend neighbor reads are L2-local. */
__device__ __forceinline__ int swz_chunk(int w) { return (w & 7) * (NCHUNK / 8) + (w >> 3); }

/* ---- K A: sd + FIR + zero-init IIR; writes y_zero (f16) + pend (f32x4) ----
   block = chunk, thread = batch lane b. */
__global__ __launch_bounds__(512, 4) void k_stage(const float* __restrict__ signal,
                                                  const float* __restrict__ noise,
                                                  const Coefs k,
                                                  __half* __restrict__ ybuf,
                                                  float4* __restrict__ pend4) {
    __shared__ float  part[NTAU * 8];
    __shared__ double sdsh[NTAU];

    const int tid = threadIdx.x;
    const int b   = tid;
    const int w   = tid >> 6;
    const int l   = tid & 63;
    const int c   = swz_chunk(blockIdx.x);
    const int t0  = c * CHLEN;

    /* noise window -> registers (16B-aligned: b*TAU and t0 both %4==0) */
    const float4* nb = (const float4*)(noise + (size_t)b * TAU + t0);
    float4 nr[9];
    #pragma unroll
    for (int q = 0; q < 9; ++q) nr[q] = nb[q];
    float nv[NTAU];
    #pragma unroll
    for (int q = 0; q < 9; ++q) {
        nv[4*q+0] = nr[q].x; nv[4*q+1] = nr[q].y;
        nv[4*q+2] = nr[q].z; nv[4*q+3] = nr[q].w;
    }

    /* signal window (coalesced over b) */
    float sval[NTAU];
    #pragma unroll
    for (int j = 0; j < NTAU; ++j) {
        const int tau = t0 + j;
        sval[j] = (c == 0 && tau < 4) ? 0.0f : signal[(size_t)(tau - 4) * BATCH + b];
    }

    /* per-tau batch mean: f32 wave tree + f64 combine -> sd */
    #pragma unroll
    for (int j = 0; j < NTAU; ++j) {
        float v = sval[j];
        for (int off = 32; off > 0; off >>= 1) v += __shfl_down(v, off, 64);
        if (l == 0) part[j * 8 + w] = v;
    }
    __syncthreads();
    if (tid < NTAU) {
        const double c1 = 2.0 * 1.602176563e-19 * 50000000000.0;
        const double c2 = 4.0 * 1.3806488e-23 * 300.0 * 50000000000.0 / 1000000.0;
        double ssum = 0.0;
        #pragma unroll
        for (int i = 0; i < 8; ++i) ssum += (double)part[tid * 8 + i];
        sdsh[tid] = sqrt(c1 * (ssum / 512.0 + 1e-10) + c2);
    }
    __syncthreads();

    /* FIR + zero-init IIR; y_zero -> f16, end state -> f32x4 */
    auto XN = [&](int j) -> double { return sdsh[j] * (double)nv[j] + (double)sval[j]; };
    double w0 = XN(0), w1 = XN(1), w2 = XN(2), w3 = XN(3), w4;
    double z0 = 0.0, z1 = 0.0, z2 = 0.0, z3 = 0.0;
    #pragma unroll
    for (int i = 0; i < CHLEN; ++i) {
        w4 = XN(i + 4);
        const double s = k.b0*w0 + k.b1*w1 + k.b2*w2 + k.b3*w3 + k.b4*w4;
        const double y = (c == 0 && i < 5) ? s
                       : s - (k.c0*z0 + k.c1*z1 + k.c2*z2 + k.c3*z3);
        ybuf[(size_t)(t0 + i) * BATCH + b] = __float2half((float)y);
        z0 = z1; z1 = z2; z2 = z3; z3 = y;
        w0 = w1; w1 = w2; w2 = w3; w3 = w4;
    }
    pend4[(size_t)c * BATCH + b] = make_float4((float)z0, (float)z1, (float)z2, (float)z3);
}

/* ---- K B: Horner y0 from 8 neighbor pends, homogeneous correction, add ----
   out(t0+i) = y_zero(t0+i) + h_i,  h = -(c·h-state), h-state seeded with y0(c).
   No FIR, no s: ~160 f64 FMA + f16 load + f32 store per thread. */
__global__ __launch_bounds__(256) void k_apply(const __half* __restrict__ ybuf,
                                               const Coefs k, const Mat M,
                                               const float4* __restrict__ pend4,
                                               float* __restrict__ out) {
    const int b  = (int)blockIdx.y * 256 + threadIdx.x;
    const int c  = swz_chunk(blockIdx.x);
    const int t0 = c * CHLEN;

    /* y0(c) = p(c-1) + M*(p(c-2) + M*(...)), NSER terms */
    double d0 = 0.0, d1 = 0.0, d2 = 0.0, d3 = 0.0;
    #pragma unroll
    for (int d = NSER; d >= 1; --d) {
        if (d <= c) {
            const float4 p = pend4[(size_t)(c - d) * BATCH + b];
            const double n0 = (double)p.x + M.m[0]*d0 + M.m[4]*d1 + M.m[8]*d2  + M.m[12]*d3;
            const double n1 = (double)p.y + M.m[1]*d0 + M.m[5]*d1 + M.m[9]*d2  + M.m[13]*d3;
            const double n2 = (double)p.z + M.m[2]*d0 + M.m[6]*d1 + M.m[10]*d2 + M.m[14]*d3;
            const double n3 = (double)p.w + M.m[3]*d0 + M.m[7]*d1 + M.m[11]*d2 + M.m[15]*d3;
            d0 = n0; d1 = n1; d2 = n2; d3 = n3;
        }
    }

    /* homogeneous replay + add to y_zero (c==0: d=0 -> passthrough) */
    #pragma unroll
    for (int i = 0; i < CHLEN; ++i) {
        const double h = -(k.c0*d0 + k.c1*d1 + k.c2*d2 + k.c3*d3);
        const size_t idx = (size_t)(t0 + i) * BATCH + b;
        out[idx] = (float)((double)__half2float(ybuf[idx]) + h);
        d0 = d1; d1 = d2; d2 = d3; d3 = h;
    }
}

/* ---- host: replicate _butter_lowpass exactly (f64, same algorithm) ---- */
static Coefs make_coefs() {
    const int order = 4;
    const double wn = 25000000000.0 / (0.5 / 1e-12);     /* 0.05 */
    const double warped = 4.0 * tan(M_PI * wn / 2.0);
    std::complex<double> p[4];
    for (int kk = 1; kk <= order; ++kk)
        p[kk - 1] = warped * std::exp(std::complex<double>(0.0,
                        M_PI * (2 * kk + order - 1) / (2.0 * order)));
    const double gain = warped * warped * warped * warped;
    const double fs2 = 4.0;
    std::complex<double> pz[4], prod(1.0, 0.0);
    for (int i = 0; i < 4; ++i) {
        pz[i] = (fs2 + p[i]) / (fs2 - p[i]);
        prod *= (fs2 - p[i]);
    }
    const double gz = gain * std::real(std::complex<double>(1.0, 0.0) / prod);
    std::complex<double> ac[5] = { {1,0}, {0,0}, {0,0}, {0,0}, {0,0} };
    for (int i = 0; i < 4; ++i)
        for (int j = i + 1; j >= 1; --j)
            ac[j] = ac[j] - pz[i] * ac[j - 1];
    Coefs k;
    k.b0 = gz * 1.0; k.b1 = gz * 4.0; k.b2 = gz * 6.0; k.b3 = gz * 4.0; k.b4 = gz * 1.0;
    k.c0 = std::real(ac[4]); k.c1 = std::real(ac[3]);
    k.c2 = std::real(ac[2]); k.c3 = std::real(ac[1]);
    return k;
}

static void mat_compose(const double* P, const double* Q, double* R) {
    double t[16];
    for (int j = 0; j < 4; ++j)
        for (int i = 0; i < 4; ++i) {
            double s = 0.0;
            for (int kk = 0; kk < 4; ++kk) s += P[j*4+kk] * Q[kk*4+i];
            t[j*4+i] = s;
        }
    for (int i = 0; i < 16; ++i) R[i] = t[i];
}

static Mat make_M(const Coefs& k) {
    double S[16] = {0};
    S[1*4+0] = 1.0; S[2*4+1] = 1.0; S[3*4+2] = 1.0;
    S[0*4+3] = -k.c0; S[1*4+3] = -k.c1; S[2*4+3] = -k.c2; S[3*4+3] = -k.c3;
    Mat M;
    double I[16] = {1,0,0,0, 0,1,0,0, 0,0,1,0, 0,0,0,1};
    for (int i = 0; i < 16; ++i) M.m[i] = I[i];
    for (int i = 0; i < CHLEN; ++i) mat_compose(M.m, S, M.m);
    return M;
}

extern "C" void kernel_launch(void* const* d_in, const int* in_sizes, int n_in,
                              void* d_out, int out_size, void* d_ws, size_t ws_size,
                              hipStream_t stream) {
    const float* signal = (const float*)d_in[0];
    const float* noise  = (const float*)d_in[1];
    float* out = (float*)d_out;

    const Coefs k = make_coefs();    /* host f64 math; deterministic each call */
    const Mat   M = make_M(k);

    char* ws = (char*)d_ws;
    __half* ybuf  = (__half*)ws;                 /* 16384*512*2 = 16,777,216 */
    float4* pend4 = (float4*)(ws + 16777216);    /* 512*512*16  =  4,194,304 */

    hipLaunchKernelGGL(k_stage, dim3(NCHUNK), dim3(512), 0, stream,
                       signal, noise, k, ybuf, pend4);
    hipLaunchKernelGGL(k_apply, dim3(NCHUNK, 2), dim3(256), 0, stream,
                       ybuf, k, M, pend4, out);
}